// Round 4
// baseline (2116.886 us; speedup 1.0000x reference)
//
#include <hip/hip_runtime.h>
#include <hip/hip_fp16.h>
#include <math.h>

// Problem constants
#define S_LEN 2048
#define NHEAD 16
#define EMB   2048
#define HD    128
#define KDIM  2048
// d_out layout (floats): y | k | v
#define Y_OFF 0
#define K_OFF 8388608
#define V_OFF 16777216

// ---------------------------------------------------------------------------
// Kernel 1: qkv = x @ Wc^T + bc, fused with rope-scale + scatter (unchanged;
// ~95% of fp32 FMA roofline).
// ---------------------------------------------------------------------------
__global__ __launch_bounds__(256) void gemm_rope_kernel(
    const float* __restrict__ x, const float* __restrict__ Wc,
    const float* __restrict__ bc, const float* __restrict__ fq,
    float* __restrict__ qws, float* __restrict__ out)
{
    __shared__ __align__(16) float As[32][68];
    __shared__ __align__(16) float Bs[32][68];

    const int t  = threadIdx.x;
    const int bx = blockIdx.x;
    const int by = blockIdx.y;
    const int tx = t & 15, ty = t >> 4;

    float acc[4][4] = {{0.f, 0.f, 0.f, 0.f}, {0.f, 0.f, 0.f, 0.f},
                       {0.f, 0.f, 0.f, 0.f}, {0.f, 0.f, 0.f, 0.f}};

    for (int k0 = 0; k0 < KDIM; k0 += 32) {
        #pragma unroll
        for (int p = 0; p < 2; ++p) {
            const int id  = t + (p << 8);
            const int row = id >> 3;
            const int kc  = (id & 7) << 2;
            float4 va = *(const float4*)(x + (by * 64 + row) * KDIM + k0 + kc);
            As[kc + 0][row] = va.x; As[kc + 1][row] = va.y;
            As[kc + 2][row] = va.z; As[kc + 3][row] = va.w;

            const int c = bx * 64 + row;
            int srow;
            if (c < 1024)      srow = ((c >> 6) << 7) + (c & 63);
            else if (c < 2048) srow = 2048 + (((c - 1024) >> 6) << 7) + (c & 63);
            else               srow = 4096 + (c - 2048);
            float4 vb = *(const float4*)(Wc + srow * KDIM + k0 + kc);
            Bs[kc + 0][row] = vb.x; Bs[kc + 1][row] = vb.y;
            Bs[kc + 2][row] = vb.z; Bs[kc + 3][row] = vb.w;
        }
        __syncthreads();
        #pragma unroll
        for (int kk = 0; kk < 32; ++kk) {
            float4 a = *(const float4*)(&As[kk][ty << 2]);
            float4 b = *(const float4*)(&Bs[kk][tx << 2]);
            const float av[4] = {a.x, a.y, a.z, a.w};
            const float bv[4] = {b.x, b.y, b.z, b.w};
            #pragma unroll
            for (int i = 0; i < 4; ++i)
                #pragma unroll
                for (int j = 0; j < 4; ++j)
                    acc[i][j] = fmaf(av[i], bv[j], acc[i][j]);
        }
        __syncthreads();
    }

    float* kout = out + K_OFF;
    float* vout = out + V_OFF;
    #pragma unroll
    for (int i = 0; i < 4; ++i) {
        const int r = by * 64 + (ty << 2) + i;
        const int b = r >> 11, s = r & 2047;
        #pragma unroll
        for (int j = 0; j < 4; ++j) {
            const int c = bx * 64 + (tx << 2) + j;
            if (c < 2048) {
                const int sec = c >> 10;
                const int cc  = c & 1023;
                const int h = cc >> 6, d2 = cc & 63;
                const float val = (acc[i][j] + bc[sec * 2048 + h * 128 + d2]) * fq[s * 64 + d2];
                const int o = ((b * 16 + h) * 2048 + s) * 128 + d2;
                if (sec == 0) { qws[o] = val;  qws[o + 64] = val; }
                else          { kout[o] = val; kout[o + 64] = val; }
            } else {
                const int cc = c - 2048;
                const int h = cc >> 7, d = cc & 127;
                vout[((b * 16 + h) * 2048 + s) * 128 + d] = acc[i][j] + bc[4096 + cc];
            }
        }
    }
}

// ---------------------------------------------------------------------------
// Kernel 2: register-tiled flash attention, fp32 logits.
// Block: 256 threads (tr=t>>4, tc=t&15), QB=128 q-rows, KB=64 keys, 32 tiles.
// Thread owns S[8 qr][4 key] and O[8 qr][8 d].
// LDS: Qt[d][qr] 64KB | Kt[d][key^swz] 32KB | Vs[key][d] 32KB |
//      Ps[key][qr] fp16 pad 136 17KB  -> ~145KB, 1 block/CU.
// Kt swizzle: col' = key ^ (((d>>2)&15)<<2)  (mask bits 2..5: keeps 4-key
// b128 frags contiguous; spreads the 16 tc-lanes over all banks on read).
// Async staging: next tile's K/V global loads issued before step1, written
// to LDS after the post-step3 barrier (T14).
// ---------------------------------------------------------------------------
__global__ __launch_bounds__(256, 1) void attn_kernel(
    const float* __restrict__ qws, const float* __restrict__ kbuf,
    const float* __restrict__ vbuf, float* __restrict__ y)
{
    __shared__ __align__(16) float  Qt[128][128];  // [d][qr]
    __shared__ __align__(16) float  Kt[128][64];   // [d][key^swz]
    __shared__ __align__(16) float  Vs[64][128];   // [key][d]
    __shared__ __align__(16) __half Ps[64][136];   // [key][qr], padded

    const int t   = threadIdx.x;
    const int bid = blockIdx.x;
    const int bh  = bid & 31;
    const int qb  = bid >> 5;
    const int tr  = t >> 4;
    const int tc  = t & 15;
    const int s0  = qb << 7;
    const int fi  = t & 31;      // staging: float4 chunk in row
    const int r0  = t >> 5;      // staging: 0..7

    const float* qp = qws  + (size_t)bh * (2048 * 128);
    const float* kb = kbuf + (size_t)bh * (2048 * 128);
    const float* vb = vbuf + (size_t)bh * (2048 * 128);

    // ---- stage Q transposed (one-time; write conflicts amortized)
    #pragma unroll
    for (int l = 0; l < 16; ++l) {
        const int qr = r0 + (l << 3);
        float4 v4 = *(const float4*)(qp + (size_t)(s0 + qr) * 128 + (fi << 2));
        Qt[(fi << 2) + 0][qr] = v4.x;
        Qt[(fi << 2) + 1][qr] = v4.y;
        Qt[(fi << 2) + 2][qr] = v4.z;
        Qt[(fi << 2) + 3][qr] = v4.w;
    }

    // ---- stage K (transposed+swizzled) and V for tile 0
    const int kswz = (fi & 15) << 2;   // == ((d>>2)&15)<<2 for d=4*fi+e
    {
        #pragma unroll
        for (int l = 0; l < 8; ++l) {
            const int key = r0 + (l << 3);
            const size_t g = (size_t)key * 128 + (fi << 2);
            float4 k4 = *(const float4*)(kb + g);
            float4 v4 = *(const float4*)(vb + g);
            const int kc = key ^ kswz;
            Kt[(fi << 2) + 0][kc] = k4.x;
            Kt[(fi << 2) + 1][kc] = k4.y;
            Kt[(fi << 2) + 2][kc] = k4.z;
            Kt[(fi << 2) + 3][kc] = k4.w;
            *(float4*)(&Vs[key][fi << 2]) = v4;
        }
    }
    __syncthreads();

    float accO[8][8];
    #pragma unroll
    for (int i = 0; i < 8; ++i)
        #pragma unroll
        for (int j = 0; j < 8; ++j) accO[i][j] = 0.f;
    float mrow[8], lrow[8];
    #pragma unroll
    for (int i = 0; i < 8; ++i) { mrow[i] = -INFINITY; lrow[i] = 0.f; }

    const float scale = 0.08838834764831845f;  // 1/sqrt(128)

    for (int kt = 0; kt < 32; ++kt) {
        // ---- issue next tile's global loads into registers (overlap compute)
        float4 kreg[8], vreg[8];
        if (kt < 31) {
            const size_t base = (size_t)(kt + 1) * 64 * 128;
            #pragma unroll
            for (int l = 0; l < 8; ++l) {
                const int key = r0 + (l << 3);
                const size_t g = base + (size_t)key * 128 + (fi << 2);
                kreg[l] = *(const float4*)(kb + g);
                vreg[l] = *(const float4*)(vb + g);
            }
        }

        // ---- step 1: S[8][4] = Q . K^T  (fp32 fmaf chain, d ascending)
        float sv[8][4];
        #pragma unroll
        for (int i = 0; i < 8; ++i)
            #pragma unroll
            for (int j = 0; j < 4; ++j) sv[i][j] = 0.f;

        for (int d0 = 0; d0 < 128; d0 += 4) {
            const int kbase = (tc << 2) ^ (((d0 >> 2) & 15) << 2);
            #pragma unroll
            for (int dd = 0; dd < 4; ++dd) {
                const int d = d0 + dd;
                float4 a0 = *(const float4*)(&Qt[d][tr << 3]);
                float4 a1 = *(const float4*)(&Qt[d][(tr << 3) + 4]);
                float4 kv = *(const float4*)(&Kt[d][kbase]);
                const float av[8] = {a0.x, a0.y, a0.z, a0.w, a1.x, a1.y, a1.z, a1.w};
                const float bv[4] = {kv.x, kv.y, kv.z, kv.w};
                #pragma unroll
                for (int i = 0; i < 8; ++i)
                    #pragma unroll
                    for (int j = 0; j < 4; ++j)
                        sv[i][j] = fmaf(av[i], bv[j], sv[i][j]);
            }
        }

        // ---- softmax update (stats per q-row, reduced over 16 tc lanes)
        #pragma unroll
        for (int i = 0; i < 8; ++i) {
            #pragma unroll
            for (int j = 0; j < 4; ++j) sv[i][j] *= scale;
            float mx = fmaxf(fmaxf(sv[i][0], sv[i][1]), fmaxf(sv[i][2], sv[i][3]));
            mx = fmaxf(mx, __shfl_xor(mx, 1));
            mx = fmaxf(mx, __shfl_xor(mx, 2));
            mx = fmaxf(mx, __shfl_xor(mx, 4));
            mx = fmaxf(mx, __shfl_xor(mx, 8));
            const float mn = fmaxf(mrow[i], mx);
            const float al = __expf(mrow[i] - mn);
            mrow[i] = mn;
            float ps = 0.f;
            #pragma unroll
            for (int j = 0; j < 4; ++j) {
                const float p = __expf(sv[i][j] - mn);
                sv[i][j] = p;
                ps += p;
            }
            ps += __shfl_xor(ps, 1);
            ps += __shfl_xor(ps, 2);
            ps += __shfl_xor(ps, 4);
            ps += __shfl_xor(ps, 8);
            lrow[i] = lrow[i] * al + ps;
            #pragma unroll
            for (int j = 0; j < 8; ++j) accO[i][j] *= al;
        }

        // ---- write P (fp16) to LDS: Ps[key][qr]
        #pragma unroll
        for (int j = 0; j < 4; ++j) {
            __half2 h[4];
            #pragma unroll
            for (int q = 0; q < 4; ++q) {
                __half2 hh;
                hh.x = __float2half_rn(sv[2 * q][j]);
                hh.y = __float2half_rn(sv[2 * q + 1][j]);
                h[q] = hh;
            }
            *(float4*)(&Ps[(tc << 2) + j][tr << 3]) = *(float4*)h;
        }
        __syncthreads();   // Ps visible to all

        // ---- step 3: O += P . V
        for (int key = 0; key < 64; ++key) {
            float4 praw = *(const float4*)(&Ps[key][tr << 3]);
            const __half2* ph = (const __half2*)&praw;
            float pv[8];
            #pragma unroll
            for (int q = 0; q < 4; ++q) {
                pv[2 * q]     = __low2float(ph[q]);
                pv[2 * q + 1] = __high2float(ph[q]);
            }
            float4 v0 = *(const float4*)(&Vs[key][tc << 2]);
            float4 v1 = *(const float4*)(&Vs[key][64 + (tc << 2)]);
            const float vv[8] = {v0.x, v0.y, v0.z, v0.w, v1.x, v1.y, v1.z, v1.w};
            #pragma unroll
            for (int i = 0; i < 8; ++i)
                #pragma unroll
                for (int j = 0; j < 8; ++j)
                    accO[i][j] = fmaf(pv[i], vv[j], accO[i][j]);
        }

        // ---- commit staged K/V for next tile
        if (kt < 31) {
            __syncthreads();   // all done reading Kt/Vs of this tile
            #pragma unroll
            for (int l = 0; l < 8; ++l) {
                const int key = r0 + (l << 3);
                const int kc  = key ^ kswz;
                Kt[(fi << 2) + 0][kc] = kreg[l].x;
                Kt[(fi << 2) + 1][kc] = kreg[l].y;
                Kt[(fi << 2) + 2][kc] = kreg[l].z;
                Kt[(fi << 2) + 3][kc] = kreg[l].w;
                *(float4*)(&Vs[key][fi << 2]) = vreg[l];
            }
            __syncthreads();   // staged data visible before next step1
        }
    }

    // ---- epilogue: normalize and store
    const int b = bh >> 4, h = bh & 15;
    #pragma unroll
    for (int i = 0; i < 8; ++i) {
        const float inv = 1.f / lrow[i];
        const int srow = s0 + (tr << 3) + i;
        float* yp = y + ((size_t)(b * 2048 + srow)) * 2048 + h * 128;
        float4 o0, o1;
        o0.x = accO[i][0] * inv; o0.y = accO[i][1] * inv;
        o0.z = accO[i][2] * inv; o0.w = accO[i][3] * inv;
        o1.x = accO[i][4] * inv; o1.y = accO[i][5] * inv;
        o1.z = accO[i][6] * inv; o1.w = accO[i][7] * inv;
        *(float4*)(yp + (tc << 2))      = o0;
        *(float4*)(yp + 64 + (tc << 2)) = o1;
    }
}

extern "C" void kernel_launch(void* const* d_in, const int* in_sizes, int n_in,
                              void* d_out, int out_size, void* d_ws, size_t ws_size,
                              hipStream_t stream)
{
    const float* x  = (const float*)d_in[0];
    const float* Wc = (const float*)d_in[1];
    const float* bc = (const float*)d_in[2];
    const float* fq = (const float*)d_in[3];
    float* out = (float*)d_out;
    float* qws = (float*)d_ws;   // q, (B,H,S,D) fp32 = 64 MiB

    dim3 g1(64, 64);
    gemm_rope_kernel<<<g1, 256, 0, stream>>>(x, Wc, bc, fq, qws, out);
    attn_kernel<<<512, 256, 0, stream>>>(qws, out + K_OFF, out + V_OFF, out + Y_OFF);
}

// Round 5
// 1681.555 us; speedup vs baseline: 1.2589x; 1.2589x over previous
//
#include <hip/hip_runtime.h>
#include <hip/hip_fp16.h>
#include <math.h>

// Problem constants
#define KDIM  2048
// d_out layout (floats): y | k | v
#define Y_OFF 0
#define K_OFF 8388608
#define V_OFF 16777216

// ---------------------------------------------------------------------------
// Kernel 1: qkv = x @ Wc^T + bc, fused with rope-scale + scatter.
// q is written COMPACT (64 dims) and pre-multiplied by 2.0 (exact), since
// q.k over 128 duplicated dims == Sum_64 (2*qh)*kh.
// ---------------------------------------------------------------------------
__global__ __launch_bounds__(256) void gemm_rope_kernel(
    const float* __restrict__ x, const float* __restrict__ Wc,
    const float* __restrict__ bc, const float* __restrict__ fq,
    float* __restrict__ qws, float* __restrict__ out)
{
    __shared__ __align__(16) float As[32][68];
    __shared__ __align__(16) float Bs[32][68];

    const int t  = threadIdx.x;
    const int bx = blockIdx.x;
    const int by = blockIdx.y;
    const int tx = t & 15, ty = t >> 4;

    float acc[4][4] = {{0.f, 0.f, 0.f, 0.f}, {0.f, 0.f, 0.f, 0.f},
                       {0.f, 0.f, 0.f, 0.f}, {0.f, 0.f, 0.f, 0.f}};

    for (int k0 = 0; k0 < KDIM; k0 += 32) {
        #pragma unroll
        for (int p = 0; p < 2; ++p) {
            const int id  = t + (p << 8);
            const int row = id >> 3;
            const int kc  = (id & 7) << 2;
            float4 va = *(const float4*)(x + (by * 64 + row) * KDIM + k0 + kc);
            As[kc + 0][row] = va.x; As[kc + 1][row] = va.y;
            As[kc + 2][row] = va.z; As[kc + 3][row] = va.w;

            const int c = bx * 64 + row;
            int srow;
            if (c < 1024)      srow = ((c >> 6) << 7) + (c & 63);
            else if (c < 2048) srow = 2048 + (((c - 1024) >> 6) << 7) + (c & 63);
            else               srow = 4096 + (c - 2048);
            float4 vb = *(const float4*)(Wc + srow * KDIM + k0 + kc);
            Bs[kc + 0][row] = vb.x; Bs[kc + 1][row] = vb.y;
            Bs[kc + 2][row] = vb.z; Bs[kc + 3][row] = vb.w;
        }
        __syncthreads();
        #pragma unroll
        for (int kk = 0; kk < 32; ++kk) {
            float4 a = *(const float4*)(&As[kk][ty << 2]);
            float4 b = *(const float4*)(&Bs[kk][tx << 2]);
            const float av[4] = {a.x, a.y, a.z, a.w};
            const float bv[4] = {b.x, b.y, b.z, b.w};
            #pragma unroll
            for (int i = 0; i < 4; ++i)
                #pragma unroll
                for (int j = 0; j < 4; ++j)
                    acc[i][j] = fmaf(av[i], bv[j], acc[i][j]);
        }
        __syncthreads();
    }

    float* kout = out + K_OFF;
    float* vout = out + V_OFF;
    #pragma unroll
    for (int i = 0; i < 4; ++i) {
        const int r = by * 64 + (ty << 2) + i;
        const int b = r >> 11, s = r & 2047;
        #pragma unroll
        for (int j = 0; j < 4; ++j) {
            const int c = bx * 64 + (tx << 2) + j;
            if (c < 2048) {
                const int sec = c >> 10;
                const int cc  = c & 1023;
                const int h = cc >> 6, d2 = cc & 63;
                const float val = (acc[i][j] + bc[sec * 2048 + h * 128 + d2]) * fq[s * 64 + d2];
                if (sec == 0) {
                    qws[((size_t)(b * 16 + h) * 2048 + s) * 64 + d2] = 2.0f * val;
                } else {
                    const size_t o = ((size_t)(b * 16 + h) * 2048 + s) * 128 + d2;
                    kout[o] = val; kout[o + 64] = val;
                }
            } else {
                const int cc = c - 2048;
                const int h = cc >> 7, d = cc & 127;
                vout[((size_t)(b * 16 + h) * 2048 + s) * 128 + d] = acc[i][j] + bc[4096 + cc];
            }
        }
    }
}

// ---------------------------------------------------------------------------
// Kernel 2: register-tiled flash attention.
// Block: 256 threads (tr=t>>4, tc=t&15), QB=128 q-rows, KB=64 keys, 32 tiles.
// QK^T runs on COMPACT 64-dim q/k (q pre-doubled): half the FMA of R4.
// LDS (80 KB exactly -> 2 blocks/CU, 2 waves/SIMD):
//   Qt[64 d][128 qr] fp32 32KB | Kt[64 d][64 key] fp32 16KB |
//   Vs[64 key][128 d] fp16 16KB | Ps[64 key][128 qr] fp16 16KB
// Thread owns S[8 qr][4 key] and O[8 qr][8 d]. Reg-prefetch of next K/V tile.
// ---------------------------------------------------------------------------
__global__ __launch_bounds__(256, 2) void attn_kernel(
    const float* __restrict__ qws, const float* __restrict__ kbuf,
    const float* __restrict__ vbuf, float* __restrict__ y)
{
    __shared__ __align__(16) float  Qt[64][128];
    __shared__ __align__(16) float  Kt[64][64];
    __shared__ __align__(16) __half Vs[64][128];
    __shared__ __align__(16) __half Ps[64][128];

    const int t   = threadIdx.x;
    const int bid = blockIdx.x;
    const int bh  = bid & 31;
    const int qb  = bid >> 5;
    const int tr  = t >> 4;
    const int tc  = t & 15;
    const int s0  = qb << 7;

    const float* qp = qws  + (size_t)bh * (2048 * 64);
    const float* kb = kbuf + (size_t)bh * (2048 * 128);
    const float* vb = vbuf + (size_t)bh * (2048 * 128);

    // K staging mapping: thread -> key kk0=t>>2, d-segment sg=t&3 (16 floats)
    const int kk0 = t >> 2, sg = t & 3;
    // V staging mapping: thread -> rows r0+8l, float4 chunk fi
    const int fi = t & 31, r0 = t >> 5;

    // ---- stage Q transposed (compact 64-d): qr=t&127, d-half = (t>>7)*32
    {
        const int qr = t & 127;
        const int dh = (t >> 7) << 5;
        const float* src = qp + (size_t)(s0 + qr) * 64 + dh;
        #pragma unroll
        for (int i = 0; i < 8; ++i) {
            float4 v4 = *(const float4*)(src + (i << 2));
            Qt[dh + (i << 2) + 0][qr] = v4.x;
            Qt[dh + (i << 2) + 1][qr] = v4.y;
            Qt[dh + (i << 2) + 2][qr] = v4.z;
            Qt[dh + (i << 2) + 3][qr] = v4.w;
        }
    }
    // ---- stage K/V tile 0
    {
        #pragma unroll
        for (int i = 0; i < 4; ++i) {
            float4 k4 = *(const float4*)(kb + (size_t)kk0 * 128 + sg * 16 + (i << 2));
            Kt[sg * 16 + (i << 2) + 0][kk0] = k4.x;
            Kt[sg * 16 + (i << 2) + 1][kk0] = k4.y;
            Kt[sg * 16 + (i << 2) + 2][kk0] = k4.z;
            Kt[sg * 16 + (i << 2) + 3][kk0] = k4.w;
        }
        #pragma unroll
        for (int l = 0; l < 8; ++l) {
            const int key = r0 + (l << 3);
            float4 v4 = *(const float4*)(vb + (size_t)key * 128 + (fi << 2));
            __half2 h0 = __floats2half2_rn(v4.x, v4.y);
            __half2 h1 = __floats2half2_rn(v4.z, v4.w);
            float2 w; ((__half2*)&w)[0] = h0; ((__half2*)&w)[1] = h1;
            *(float2*)(&Vs[key][fi << 2]) = w;
        }
    }
    __syncthreads();

    float accO[8][8];
    #pragma unroll
    for (int i = 0; i < 8; ++i)
        #pragma unroll
        for (int j = 0; j < 8; ++j) accO[i][j] = 0.f;
    float mrow[8], lrow[8];
    #pragma unroll
    for (int i = 0; i < 8; ++i) { mrow[i] = -INFINITY; lrow[i] = 0.f; }

    const float scale = 0.08838834764831845f;  // 1/sqrt(128)

    for (int kt = 0; kt < 32; ++kt) {
        // ---- prefetch next tile's K/V into registers
        float4 kreg[4], vreg[8];
        if (kt < 31) {
            const size_t base = (size_t)(kt + 1) * 64 * 128;
            #pragma unroll
            for (int i = 0; i < 4; ++i)
                kreg[i] = *(const float4*)(kb + base + (size_t)kk0 * 128 + sg * 16 + (i << 2));
            #pragma unroll
            for (int l = 0; l < 8; ++l) {
                const int key = r0 + (l << 3);
                vreg[l] = *(const float4*)(vb + base + (size_t)key * 128 + (fi << 2));
            }
        }

        // ---- step 1: S[8][4] = Qc . Kc^T over 64 compact dims
        float sv[8][4];
        #pragma unroll
        for (int i = 0; i < 8; ++i)
            #pragma unroll
            for (int j = 0; j < 4; ++j) sv[i][j] = 0.f;

        #pragma unroll 4
        for (int d = 0; d < 64; ++d) {
            float4 a0 = *(const float4*)(&Qt[d][tr << 3]);
            float4 a1 = *(const float4*)(&Qt[d][(tr << 3) + 4]);
            float4 kv = *(const float4*)(&Kt[d][tc << 2]);
            const float av[8] = {a0.x, a0.y, a0.z, a0.w, a1.x, a1.y, a1.z, a1.w};
            const float bv[4] = {kv.x, kv.y, kv.z, kv.w};
            #pragma unroll
            for (int i = 0; i < 8; ++i)
                #pragma unroll
                for (int j = 0; j < 4; ++j)
                    sv[i][j] = fmaf(av[i], bv[j], sv[i][j]);
        }

        // ---- softmax update
        #pragma unroll
        for (int i = 0; i < 8; ++i) {
            #pragma unroll
            for (int j = 0; j < 4; ++j) sv[i][j] *= scale;
            float mx = fmaxf(fmaxf(sv[i][0], sv[i][1]), fmaxf(sv[i][2], sv[i][3]));
            mx = fmaxf(mx, __shfl_xor(mx, 1));
            mx = fmaxf(mx, __shfl_xor(mx, 2));
            mx = fmaxf(mx, __shfl_xor(mx, 4));
            mx = fmaxf(mx, __shfl_xor(mx, 8));
            const float mn = fmaxf(mrow[i], mx);
            const float al = __expf(mrow[i] - mn);
            mrow[i] = mn;
            float ps = 0.f;
            #pragma unroll
            for (int j = 0; j < 4; ++j) {
                const float p = __expf(sv[i][j] - mn);
                sv[i][j] = p;
                ps += p;
            }
            ps += __shfl_xor(ps, 1);
            ps += __shfl_xor(ps, 2);
            ps += __shfl_xor(ps, 4);
            ps += __shfl_xor(ps, 8);
            lrow[i] = lrow[i] * al + ps;
            #pragma unroll
            for (int j = 0; j < 8; ++j) accO[i][j] *= al;
        }

        // ---- write P (fp16): Ps[key][qr]
        #pragma unroll
        for (int j = 0; j < 4; ++j) {
            __half2 h[4];
            #pragma unroll
            for (int q = 0; q < 4; ++q) {
                __half2 hh;
                hh.x = __float2half_rn(sv[2 * q][j]);
                hh.y = __float2half_rn(sv[2 * q + 1][j]);
                h[q] = hh;
            }
            *(float4*)(&Ps[(tc << 2) + j][tr << 3]) = *(float4*)h;
        }
        __syncthreads();

        // ---- step 3: O += P . V  (V fp16, full 128 d)
        for (int key = 0; key < 64; ++key) {
            float4 praw = *(const float4*)(&Ps[key][tr << 3]);
            const __half2* ph = (const __half2*)&praw;
            float pv[8];
            #pragma unroll
            for (int q = 0; q < 4; ++q) {
                pv[2 * q]     = __low2float(ph[q]);
                pv[2 * q + 1] = __high2float(ph[q]);
            }
            float2 vr0 = *(const float2*)(&Vs[key][tc << 2]);
            float2 vr1 = *(const float2*)(&Vs[key][64 + (tc << 2)]);
            const __half2* vh0 = (const __half2*)&vr0;
            const __half2* vh1 = (const __half2*)&vr1;
            const float vv[8] = {
                __low2float(vh0[0]), __high2float(vh0[0]),
                __low2float(vh0[1]), __high2float(vh0[1]),
                __low2float(vh1[0]), __high2float(vh1[0]),
                __low2float(vh1[1]), __high2float(vh1[1])};
            #pragma unroll
            for (int i = 0; i < 8; ++i)
                #pragma unroll
                for (int j = 0; j < 8; ++j)
                    accO[i][j] = fmaf(pv[i], vv[j], accO[i][j]);
        }

        // ---- commit staged K/V
        if (kt < 31) {
            __syncthreads();
            #pragma unroll
            for (int i = 0; i < 4; ++i) {
                Kt[sg * 16 + (i << 2) + 0][kk0] = kreg[i].x;
                Kt[sg * 16 + (i << 2) + 1][kk0] = kreg[i].y;
                Kt[sg * 16 + (i << 2) + 2][kk0] = kreg[i].z;
                Kt[sg * 16 + (i << 2) + 3][kk0] = kreg[i].w;
            }
            #pragma unroll
            for (int l = 0; l < 8; ++l) {
                const int key = r0 + (l << 3);
                __half2 h0 = __floats2half2_rn(vreg[l].x, vreg[l].y);
                __half2 h1 = __floats2half2_rn(vreg[l].z, vreg[l].w);
                float2 w; ((__half2*)&w)[0] = h0; ((__half2*)&w)[1] = h1;
                *(float2*)(&Vs[key][fi << 2]) = w;
            }
            __syncthreads();
        }
    }

    // ---- epilogue
    const int b = bh >> 4, h = bh & 15;
    #pragma unroll
    for (int i = 0; i < 8; ++i) {
        const float inv = 1.f / lrow[i];
        const int srow = s0 + (tr << 3) + i;
        float* yp = y + ((size_t)(b * 2048 + srow)) * 2048 + h * 128;
        float4 o0, o1;
        o0.x = accO[i][0] * inv; o0.y = accO[i][1] * inv;
        o0.z = accO[i][2] * inv; o0.w = accO[i][3] * inv;
        o1.x = accO[i][4] * inv; o1.y = accO[i][5] * inv;
        o1.z = accO[i][6] * inv; o1.w = accO[i][7] * inv;
        *(float4*)(yp + (tc << 2))      = o0;
        *(float4*)(yp + 64 + (tc << 2)) = o1;
    }
}

extern "C" void kernel_launch(void* const* d_in, const int* in_sizes, int n_in,
                              void* d_out, int out_size, void* d_ws, size_t ws_size,
                              hipStream_t stream)
{
    const float* x  = (const float*)d_in[0];
    const float* Wc = (const float*)d_in[1];
    const float* bc = (const float*)d_in[2];
    const float* fq = (const float*)d_in[3];
    float* out = (float*)d_out;
    float* qws = (float*)d_ws;   // compact q, (B,H,S,64) fp32 = 16 MiB

    dim3 g1(64, 64);
    gemm_rope_kernel<<<g1, 256, 0, stream>>>(x, Wc, bc, fq, qws, out);
    attn_kernel<<<512, 256, 0, stream>>>(qws, out + K_OFF, out + V_OFF, out + Y_OFF);
}